// Round 1
// 553.024 us; speedup vs baseline: 1.0937x; 1.0937x over previous
//
#include <hip/hip_runtime.h>
#include <hip/hip_bf16.h>
#include <stdint.h>

#define D_IN    1408
#define D_HID   256
#define N_HEADS 32
#define BATCH   16384

#define BM 256            // rows per block
#define BN 256            // full head of hidden units
#define BK 64
#define KTILES (D_IN / BK)   // 22, exact

typedef unsigned short u16;
typedef short short8 __attribute__((ext_vector_type(8)));
typedef float f32x4 __attribute__((ext_vector_type(4)));

// All inputs and the output are float32 (reference dtypes); compute is bf16
// MFMA (absmax 7.8e-3 vs threshold 2.4e-2, verified previous session).
__device__ __forceinline__ u16 f2b(float f) {
  __hip_bfloat16 h = __float2bfloat16(f);
  return *(u16*)&h;
}

// async global->LDS DMA, 16B/lane; LDS dest = wave-uniform base + lane*16.
__device__ __forceinline__ void gload_lds16(const void* g, void* l) {
  __builtin_amdgcn_global_load_lds(
      (const __attribute__((address_space(1))) uint32_t*)((const uint32_t*)g),
      (__attribute__((address_space(3))) uint32_t*)((uint32_t*)l),
      16, 0, 0);
}

// ---------------------------------------------------------------------------
// Kernel 0: X f32 [16384][1408] -> Xb bf16
// ---------------------------------------------------------------------------
__global__ void convert_x(const float4* __restrict__ X, ushort4* __restrict__ Xb) {
  int i = blockIdx.x * blockDim.x + threadIdx.x;   // 5,767,168 float4s exactly
  float4 v = X[i];
  ushort4 o;
  o.x = f2b(v.x); o.y = f2b(v.y); o.z = f2b(v.z); o.w = f2b(v.w);
  Xb[i] = o;
}

// ---------------------------------------------------------------------------
// Kernel 1: W1 f32 [32][1408][256] -> W1T bf16 [32][256][1408]
// ---------------------------------------------------------------------------
__global__ void transpose_w1(const float* __restrict__ W1, u16* __restrict__ W1T) {
  __shared__ u16 tile[64][65];
  const int h = blockIdx.z;
  const int f0 = blockIdx.x * 64;
  const int o0 = blockIdx.y * 64;
  const int tx = threadIdx.x;       // 0..63
  const int ty = threadIdx.y;       // 0..3
  const size_t ib = (size_t)h * D_IN * D_HID;
  #pragma unroll
  for (int i = ty; i < 64; i += 4)
    tile[i][tx] = f2b(W1[ib + (size_t)(f0 + i) * D_HID + o0 + tx]);
  __syncthreads();
  const size_t ob = (size_t)h * D_HID * D_IN;
  #pragma unroll
  for (int i = ty; i < 64; i += 4)
    W1T[ob + (size_t)(o0 + i) * D_IN + f0 + tx] = tile[tx][i];
}

// ---------------------------------------------------------------------------
// Kernel 2: 256x256 8-wave 8-phase-style fused GEMM (T3+T4+T5 port).
//
// Prev rev (64x256, 4 waves, vmcnt(0)+2 barriers per K-tile) sat at the m97
// structural ceiling: MfmaUtil 37.6%. This rev ports the verified 256"-class
// 8-phase schedule:
//   - 8 waves (2M x 4N), INTERLEAVED wave tiling: wave (wm,wn) owns rows
//     {mf*32+wm*16}, cols {nf*64+wn*16}, so quadrant (qm,qn) of every wave
//     reads exactly LDS half A[qm] / B[qn] -> halves free mid-iteration.
//   - double-buffered LDS (2 x (A 32KB + B 32KB) = 128 KB, 1 block/CU).
//   - 4 phases per K-tile, each: {ds_read frag subtile | 1 half-tile DMA
//     stage} -> barrier -> setprio(1) 16xMFMA setprio(0) -> barrier.
//     Frag caching (A per-qm, B whole iter) => 24 ds_read_b128 / K-tile.
//   - COUNTED vmcnt(4) once per K-tile before the iteration-end barrier
//     (never drain to 0 in steady state). Stage order per iter t:
//     ph0: A1(t+1)->buf^1   (freed: buf^1 fully read last iter)
//     ph1: B0(t+1)->buf^1
//     ph2: A0(t+2)->buf     (A0(t) last read ph0; barriers ph0,ph1 passed)
//     ph3: B1(t+2)->buf     (B1(t) last read ph1)
//     vmcnt(4) allows the newest 2 halves {A0(t+2),B1(t+2)} outstanding and
//     guarantees tile t+1 fully landed. X halves fly ~6 phases (HBM-latency
//     covered); W1T halves 3 phases (L2-resident, covered).
//   - last 2 iterations stage nothing ahead -> their end-wait must be
//     vmcnt(0) (the newest-2 rule no longer protects A1/B0(t+1)).
// XOR-swizzled LDS exactly as before (chunk ^= row&7, both sides; measured
// 0 bank conflicts). XCD decode: xcd=id&7 owns heads 4*xcd..+3; 4 heads of
// one mtile are consecutive -> X L2 reuse.
// ---------------------------------------------------------------------------
__global__ __launch_bounds__(512, 2) void mano_gemm(
    const u16* __restrict__ X,               // [16384][1408] bf16 (ws)
    const u16* __restrict__ W1T,             // [32][256][1408] bf16 (ws)
    const float* __restrict__ b1,            // [32][256] f32
    const float* __restrict__ W2,            // [32][256][3] f32
    const float* __restrict__ b2,            // [32][3] f32
    float* __restrict__ out)                 // [16384][96] f32 (d_out)
{
  __shared__ __align__(16) u16 As[2][BM * BK];   // 2 x 32 KB
  __shared__ __align__(16) u16 Bs[2][BN * BK];   // 2 x 32 KB

  const int tid  = threadIdx.x;
  const int lane = tid & 63;
  const int wid  = tid >> 6;        // 0..7
  const int quad = lane >> 4;
  const int l15  = lane & 15;
  const int wm   = wid >> 2;        // 0..1
  const int wn   = wid & 3;         // 0..3

  const int id    = blockIdx.x;     // 0..2047
  const int xcd   = id & 7;
  const int s     = id >> 3;        // 0..255 per XCD
  const int head  = xcd * 4 + (s & 3);
  const int mtile = s >> 2;         // 0..63
  const int m0    = mtile * BM;

  const u16* Au = X + (size_t)m0 * D_IN;
  const u16* Bu = W1T + (size_t)head * D_HID * D_IN;

  // staging: LDS chunk ci(16B) of a 128-row half holds global
  // [row=ci>>3][k8=(ci&7)^(row&7)] (XOR pre-swizzled source, linear LDS).
  int off[2][2];   // [half][c] global u16 offset (row*D_IN + k8*8)
  #pragma unroll
  for (int c = 0; c < 2; ++c) {
    int ci = c * 512 + tid;
    int rl = ci >> 3;                 // 0..127
    int k8 = (ci & 7) ^ (rl & 7);
    #pragma unroll
    for (int h = 0; h < 2; ++h)
      off[h][c] = (h * 128 + rl) * D_IN + k8 * 8;
  }

#define STAGE_A(bufi, h, kt) do {                                          \
    _Pragma("unroll")                                                      \
    for (int c = 0; c < 2; ++c)                                            \
      gload_lds16(Au + off[h][c] + (kt) * BK,                              \
                  &As[bufi][((h) * 1024 + c * 512 + wid * 64) * 8]);       \
  } while (0)
#define STAGE_B(bufi, h, kt) do {                                          \
    _Pragma("unroll")                                                      \
    for (int c = 0; c < 2; ++c)                                            \
      gload_lds16(Bu + off[h][c] + (kt) * BK,                              \
                  &Bs[bufi][((h) * 1024 + c * 512 + wid * 64) * 8]);       \
  } while (0)

  // frag read addressing: row = mf*32+wm*16+l15 (A), nf*64+wn*16+l15 (B);
  // phys chunk = (ks*4+quad) ^ (row&7), row&7 == l15&7.
  const int wm16l = wm * 16 + l15;
  const int wn16l = wn * 16 + l15;
  const int rx  = l15 & 7;
  const int co0 = (quad ^ rx) * 16;
  const int co1 = ((4 + quad) ^ rx) * 16;

#define LDA_FRAG(mf, ks) \
  (*(const short8*)(Ab + ((mf) * 32 + wm16l) * 128 + ((ks) ? co1 : co0)))
#define LDB_FRAG(nf, ks) \
  (*(const short8*)(Bb + (nf) * 8192 + wn16l * 128 + ((ks) ? co1 : co0)))

  f32x4 acc[8][4];
  #pragma unroll
  for (int i = 0; i < 8; ++i)
    #pragma unroll
    for (int j = 0; j < 4; ++j)
      acc[i][j] = f32x4{0.f, 0.f, 0.f, 0.f};

  // ---- prologue: issue order mimics steady state so vmcnt counting holds.
  STAGE_A(0, 0, 0);   // A0(0)
  STAGE_B(0, 1, 0);   // B1(0)
  STAGE_A(0, 1, 0);   // A1(0)
  STAGE_B(0, 0, 0);   // B0(0)
  STAGE_A(1, 0, 1);   // A0(1)
  STAGE_B(1, 1, 1);   // B1(1)
  asm volatile("s_waitcnt vmcnt(4)" ::: "memory");   // tile0 landed
  __builtin_amdgcn_s_barrier();

  short8 a[4][2], b[4][2];

  for (int t = 0; t < KTILES; ++t) {
    const int buf = t & 1;
    const char* Ab = (const char*)&As[buf][0];
    const char* Bb = (const char*)&Bs[buf][0];

    // ---- phase 0: quadrant (0,0) ------ stage A1(t+1) -> buf^1
    #pragma unroll
    for (int mf = 0; mf < 4; ++mf) {
      a[mf][0] = LDA_FRAG(mf, 0);
      a[mf][1] = LDA_FRAG(mf, 1);
    }
    #pragma unroll
    for (int nf = 0; nf < 2; ++nf) {
      b[nf][0] = LDB_FRAG(nf, 0);
      b[nf][1] = LDB_FRAG(nf, 1);
    }
    if (t + 1 < KTILES) STAGE_A(buf ^ 1, 1, t + 1);
    __builtin_amdgcn_s_barrier();
    __builtin_amdgcn_s_setprio(1);
    #pragma unroll
    for (int mf = 0; mf < 4; ++mf)
      #pragma unroll
      for (int nf = 0; nf < 2; ++nf) {
        acc[mf][nf] = __builtin_amdgcn_mfma_f32_16x16x32_bf16(a[mf][0], b[nf][0], acc[mf][nf], 0, 0, 0);
        acc[mf][nf] = __builtin_amdgcn_mfma_f32_16x16x32_bf16(a[mf][1], b[nf][1], acc[mf][nf], 0, 0, 0);
      }
    __builtin_amdgcn_s_setprio(0);
    __builtin_amdgcn_s_barrier();

    // ---- phase 1: quadrant (0,1) ------ stage B0(t+1) -> buf^1
    #pragma unroll
    for (int nf = 2; nf < 4; ++nf) {
      b[nf][0] = LDB_FRAG(nf, 0);
      b[nf][1] = LDB_FRAG(nf, 1);
    }
    if (t + 1 < KTILES) STAGE_B(buf ^ 1, 0, t + 1);
    __builtin_amdgcn_s_barrier();
    __builtin_amdgcn_s_setprio(1);
    #pragma unroll
    for (int mf = 0; mf < 4; ++mf)
      #pragma unroll
      for (int nf = 2; nf < 4; ++nf) {
        acc[mf][nf] = __builtin_amdgcn_mfma_f32_16x16x32_bf16(a[mf][0], b[nf][0], acc[mf][nf], 0, 0, 0);
        acc[mf][nf] = __builtin_amdgcn_mfma_f32_16x16x32_bf16(a[mf][1], b[nf][1], acc[mf][nf], 0, 0, 0);
      }
    __builtin_amdgcn_s_setprio(0);
    __builtin_amdgcn_s_barrier();

    // ---- phase 2: quadrant (1,1) ------ stage A0(t+2) -> buf
    #pragma unroll
    for (int i = 0; i < 4; ++i) {
      a[i][0] = LDA_FRAG(4 + i, 0);
      a[i][1] = LDA_FRAG(4 + i, 1);
    }
    if (t + 2 < KTILES) STAGE_A(buf, 0, t + 2);
    __builtin_amdgcn_s_barrier();
    __builtin_amdgcn_s_setprio(1);
    #pragma unroll
    for (int i = 0; i < 4; ++i)
      #pragma unroll
      for (int nf = 2; nf < 4; ++nf) {
        acc[4 + i][nf] = __builtin_amdgcn_mfma_f32_16x16x32_bf16(a[i][0], b[nf][0], acc[4 + i][nf], 0, 0, 0);
        acc[4 + i][nf] = __builtin_amdgcn_mfma_f32_16x16x32_bf16(a[i][1], b[nf][1], acc[4 + i][nf], 0, 0, 0);
      }
    __builtin_amdgcn_s_setprio(0);
    __builtin_amdgcn_s_barrier();

    // ---- phase 3: quadrant (1,0) ------ stage B1(t+2) -> buf
    if (t + 2 < KTILES) STAGE_B(buf, 1, t + 2);
    __builtin_amdgcn_s_barrier();
    __builtin_amdgcn_s_setprio(1);
    #pragma unroll
    for (int i = 0; i < 4; ++i)
      #pragma unroll
      for (int nf = 0; nf < 2; ++nf) {
        acc[4 + i][nf] = __builtin_amdgcn_mfma_f32_16x16x32_bf16(a[i][0], b[nf][0], acc[4 + i][nf], 0, 0, 0);
        acc[4 + i][nf] = __builtin_amdgcn_mfma_f32_16x16x32_bf16(a[i][1], b[nf][1], acc[4 + i][nf], 0, 0, 0);
      }
    __builtin_amdgcn_s_setprio(0);
    // counted drain: tile t+1 must be landed; newest 2 halves may fly.
    // Last 2 iters staged nothing ahead -> must drain fully.
    if (t < KTILES - 2) {
      asm volatile("s_waitcnt vmcnt(4)" ::: "memory");
    } else {
      asm volatile("s_waitcnt vmcnt(0)" ::: "memory");
    }
    __builtin_amdgcn_s_barrier();
  }

#undef STAGE_A
#undef STAGE_B
#undef LDA_FRAG
#undef LDB_FRAG

  // ---- fused epilogue: relu(acc + b1) . W2, combine 4 wn-waves via LDS ----
  // acc[mf][nf] elem (quad,r): row = mf*32+wm*16+quad*4+r, col = nf*64+wn*16+l15
  const float* b1h = b1 + head * D_HID;
  const float* W2h = W2 + (size_t)head * D_HID * 3;

  float b1v[4], w2v[4][3];
  #pragma unroll
  for (int nf = 0; nf < 4; ++nf) {
    int col = nf * 64 + wn16l;
    b1v[nf] = b1h[col];
    #pragma unroll
    for (int p = 0; p < 3; ++p) w2v[nf][p] = W2h[col * 3 + p];
  }

  // all LDS tile reads + DMA writes drained (final vmcnt(0) + barrier above)
  float* scr = (float*)&As[0][0];   // [256 rows][3 p][4 wn] = 12 KB

  #pragma unroll
  for (int mf = 0; mf < 8; ++mf) {
    float ps[4][3];
    #pragma unroll
    for (int r = 0; r < 4; ++r)
      #pragma unroll
      for (int p = 0; p < 3; ++p) ps[r][p] = 0.f;

    #pragma unroll
    for (int nf = 0; nf < 4; ++nf)
      #pragma unroll
      for (int r = 0; r < 4; ++r) {
        float h = acc[mf][nf][r] + b1v[nf];
        h = h > 0.f ? h : 0.f;
        #pragma unroll
        for (int p = 0; p < 3; ++p)
          ps[r][p] = fmaf(h, w2v[nf][p], ps[r][p]);
      }

    // sum over the 16 column-lanes (xor on low 4 lane bits stays in-quad)
    #pragma unroll
    for (int mask = 1; mask < 16; mask <<= 1)
      #pragma unroll
      for (int r = 0; r < 4; ++r)
        #pragma unroll
        for (int p = 0; p < 3; ++p)
          ps[r][p] += __shfl_xor(ps[r][p], mask, 64);

    if (l15 == 0) {
      int row = mf * 32 + wm * 16 + quad * 4;          // +r below
      #pragma unroll
      for (int r = 0; r < 4; ++r)
        #pragma unroll
        for (int p = 0; p < 3; ++p)
          scr[((row + r) * 3 + p) * 4 + wn] = ps[r][p];
    }
  }
  __syncthreads();

  // final: sum 4 wn partials + b2 -> out (768 values, 512 threads)
  for (int i = tid; i < BM * 3; i += 512) {
    int row = i / 3, p = i - row * 3;
    float v = scr[i * 4 + 0] + scr[i * 4 + 1] + scr[i * 4 + 2] + scr[i * 4 + 3]
            + b2[head * 3 + p];
    out[(size_t)(m0 + row) * (N_HEADS * 3) + head * 3 + p] = v;
  }
}

extern "C" void kernel_launch(void* const* d_in, const int* in_sizes, int n_in,
                              void* d_out, int out_size, void* d_ws, size_t ws_size,
                              hipStream_t stream) {
  const float* X  = (const float*)d_in[0];
  const float* W1 = (const float*)d_in[1];
  const float* b1 = (const float*)d_in[2];
  const float* W2 = (const float*)d_in[3];
  const float* b2 = (const float*)d_in[4];

  // ws: Xb 46,137,344 | W1T 23,068,672  = 69,206,016 B (proven fits)
  u16* Xb  = (u16*)d_ws;
  u16* W1T = (u16*)((char*)d_ws + (size_t)BATCH * D_IN * 2);

  convert_x<<<(BATCH * D_IN / 4) / 256, 256, 0, stream>>>(
      (const float4*)X, (ushort4*)Xb);

  transpose_w1<<<dim3(D_IN / 64, D_HID / 64, N_HEADS), dim3(64, 4), 0, stream>>>(W1, W1T);

  mano_gemm<<<dim3(BATCH / BM * N_HEADS), 512, 0, stream>>>(
      Xb, W1T, b1, W2, b2, (float*)d_out);
}

// Round 2
// 552.667 us; speedup vs baseline: 1.0944x; 1.0006x over previous
//
#include <hip/hip_runtime.h>
#include <hip/hip_bf16.h>
#include <stdint.h>

#define D_IN    1408
#define D_HID   256
#define N_HEADS 32
#define BATCH   16384

#define BM 256            // rows per block
#define BN 256            // full head of hidden units
#define BK 64
#define KTILES (D_IN / BK)   // 22, exact (even -> static double-buffer parity)
#define NSEG 8               // segments per persistent block

typedef unsigned short u16;
typedef short short8 __attribute__((ext_vector_type(8)));
typedef float f32x4 __attribute__((ext_vector_type(4)));

// All inputs and the output are float32 (reference dtypes); compute is bf16
// MFMA (absmax 7.8e-3 vs threshold 2.4e-2, verified previous session + R1).
__device__ __forceinline__ u16 f2b(float f) {
  __hip_bfloat16 h = __float2bfloat16(f);
  return *(u16*)&h;
}

// async global->LDS DMA, 16B/lane; LDS dest = wave-uniform base + lane*16.
__device__ __forceinline__ void gload_lds16(const void* g, void* l) {
  __builtin_amdgcn_global_load_lds(
      (const __attribute__((address_space(1))) uint32_t*)((const uint32_t*)g),
      (__attribute__((address_space(3))) uint32_t*)((uint32_t*)l),
      16, 0, 0);
}

// ---------------------------------------------------------------------------
// Kernel 0: X f32 [16384][1408] -> Xb bf16
// ---------------------------------------------------------------------------
__global__ void convert_x(const float4* __restrict__ X, ushort4* __restrict__ Xb) {
  int i = blockIdx.x * blockDim.x + threadIdx.x;   // 5,767,168 float4s exactly
  float4 v = X[i];
  ushort4 o;
  o.x = f2b(v.x); o.y = f2b(v.y); o.z = f2b(v.z); o.w = f2b(v.w);
  Xb[i] = o;
}

// ---------------------------------------------------------------------------
// Kernel 1: W1 f32 [32][1408][256] -> W1T bf16 [32][256][1408]
// (store side vectorized to ushort4: 8B/lane instead of 2B/lane)
// ---------------------------------------------------------------------------
__global__ void transpose_w1(const float* __restrict__ W1, u16* __restrict__ W1T) {
  __shared__ u16 tile[64][68];      // pad to 68 (136B rows) for read spread
  const int h = blockIdx.z;
  const int f0 = blockIdx.x * 64;
  const int o0 = blockIdx.y * 64;
  const int tx = threadIdx.x;       // 0..63
  const int ty = threadIdx.y;       // 0..3
  const size_t ib = (size_t)h * D_IN * D_HID;
  #pragma unroll
  for (int i = ty; i < 64; i += 4)
    tile[i][tx] = f2b(W1[ib + (size_t)(f0 + i) * D_HID + o0 + tx]);
  __syncthreads();
  const size_t ob = (size_t)h * D_HID * D_IN;
  // 256 threads; 16 threads per output row (4 cols each) -> 16 rows/pass.
  #pragma unroll
  for (int pass = 0; pass < 4; ++pass) {
    int r = pass * 16 + ty * 4 + (tx >> 4);  // 0..63
    int c = (tx & 15) * 4;                   // 0..60
    ushort4 v;
    v.x = tile[c + 0][r]; v.y = tile[c + 1][r];
    v.z = tile[c + 2][r]; v.w = tile[c + 3][r];
    *(ushort4*)&W1T[ob + (size_t)(o0 + r) * D_IN + f0 + c] = v;
  }
}

// ---------------------------------------------------------------------------
// Kernel 2: PERSISTENT 256x256 8-wave 8-phase fused GEMM.
//
// R1 post-mortem: 8-phase port gave MfmaUtil 37.6->40.1 only. Residual =
// 8x generation overhead (2048 blocks / 256 CUs: cold prologue + vmcnt(0)
// tail + dead-pipe epilogue, per generation) + shallow vmcnt depth (2 halves
// vs m201's 3) + runtime-indexed LDS buffer. This rev:
//   - grid=256 persistent blocks, 1/CU. head = f(bid) CONSTANT per block
//     (W1T slice + b1/W2 L2/LDS-resident all kernel); 8 segments of mtiles.
//   - ONE continuous 176-tile pipeline: staging for segment g+1 tiles 0/1
//     issues during segment g's last iterations; epilogue VALU hides the
//     next segment's staging latency. vmcnt never drains except kernel end.
//   - uniform depth-6 schedule (m201's depth): each phase stages exactly one
//     half: ph0:B0(t+1) ph1:A0(t+2) ph2:B1(t+2) ph3:A1(t+2) (each region
//     provably free: its tile-t instance was fully consumed the prior phase).
//     Iter-end s_waitcnt vmcnt(6) => all of tile t+1 landed; 3 newest halves
//     {A0,B1,A1}(t+2) may fly. X (HBM) halves get 5-7 phases of latency
//     cover, W1T (L2-hot) >=4 phases.
//   - tile loop unrolled x2 (KTILES even) -> LDS buffer index compile-time.
//   - b1/W2/b2 preloaded to LDS once (head-constant): epilogue has NO global
//     loads -> no compiler-forced vmcnt(0) mid-pipeline. Separate scr LDS.
// XOR-swizzled LDS unchanged (R1: 0 bank conflicts). Layout bijection
// (head,mtile) <-> (bid,g): head=(bid&7)*4+((bid>>3)&3), mtile=g*8+(bid>>5).
// ---------------------------------------------------------------------------
__global__ __launch_bounds__(512, 2) void mano_gemm(
    const u16* __restrict__ X,               // [16384][1408] bf16 (ws)
    const u16* __restrict__ W1T,             // [32][256][1408] bf16 (ws)
    const float* __restrict__ b1,            // [32][256] f32
    const float* __restrict__ W2,            // [32][256][3] f32
    const float* __restrict__ b2,            // [32][3] f32
    float* __restrict__ out)                 // [16384][96] f32 (d_out)
{
  __shared__ __align__(16) u16 As[2][BM * BK];   // 2 x 32 KB
  __shared__ __align__(16) u16 Bs[2][BN * BK];   // 2 x 32 KB
  __shared__ __align__(16) float scr[3072];      // 12 KB epilogue scratch
  __shared__ float b1L[256];                     // head-constant params
  __shared__ float w2L[768];
  __shared__ float b2L[3];

  const int tid  = threadIdx.x;
  const int lane = tid & 63;
  const int wid  = tid >> 6;        // 0..7
  const int quad = lane >> 4;
  const int l15  = lane & 15;
  const int wm   = wid >> 2;        // 0..1
  const int wn   = wid & 3;         // 0..3

  const int bid  = blockIdx.x;              // 0..255
  const int head = (bid & 7) * 4 + ((bid >> 3) & 3);   // constant per block
  const int u2   = bid >> 5;                           // 0..7

  const u16* Bu = W1T + (size_t)head * D_HID * D_IN;

  // ---- head-constant params -> LDS (once; epilogues then do zero VMEM) ----
  if (tid < 256) b1L[tid] = b1[head * D_HID + tid];
  for (int i = tid; i < 768; i += 512) w2L[i] = W2[(size_t)head * D_HID * 3 + i];
  if (tid < 3)  b2L[tid] = b2[head * 3 + tid];

  // staging: LDS chunk ci(16B) of a 128-row half holds global
  // [row=ci>>3][k8=(ci&7)^(row&7)] (XOR pre-swizzled source, linear LDS).
  int off[2][2];   // [half][c] global u16 offset (row*D_IN + k8*8)
  #pragma unroll
  for (int c = 0; c < 2; ++c) {
    int ci = c * 512 + tid;
    int rl = ci >> 3;                 // 0..127
    int k8 = (ci & 7) ^ (rl & 7);
    #pragma unroll
    for (int h = 0; h < 2; ++h)
      off[h][c] = (h * 128 + rl) * D_IN + k8 * 8;
  }

#define STG_A(BI, H, P) do { _Pragma("unroll")                                 \
    for (int c = 0; c < 2; ++c)                                                \
      gload_lds16((P) + off[H][c],                                             \
                  &As[BI][((H) * 1024 + c * 512 + wid * 64) * 8]); } while (0)
#define STG_B(BI, H, P) do { _Pragma("unroll")                                 \
    for (int c = 0; c < 2; ++c)                                                \
      gload_lds16((P) + off[H][c],                                             \
                  &Bs[BI][((H) * 1024 + c * 512 + wid * 64) * 8]); } while (0)

  // frag read addressing: A row = mf*32+wm*16+l15, B row = nf*64+wn*16+l15;
  // phys chunk = (ks*4+quad) ^ (row&7), row&7 == l15&7.
  const int wm16l = wm * 16 + l15;
  const int wn16l = wn * 16 + l15;
  const int rx  = l15 & 7;
  const int co0 = (quad ^ rx) * 16;
  const int co1 = ((4 + quad) ^ rx) * 16;

#define LDAF(BI, mf, ks)                                                       \
  (*(const short8*)((const char*)&As[BI][0] +                                  \
                    ((mf) * 32 + wm16l) * 128 + ((ks) ? co1 : co0)))
#define LDBF(BI, nf, ks)                                                       \
  (*(const short8*)((const char*)&Bs[BI][0] +                                  \
                    (nf) * 8192 + wn16l * 128 + ((ks) ? co1 : co0)))
#define MM(mi, nj, ks)                                                         \
  acc[mi][nj] = __builtin_amdgcn_mfma_f32_16x16x32_bf16(                       \
      a[(mi) & 3][ks], b[nj][ks], acc[mi][nj], 0, 0, 0)

  f32x4 acc[8][4];
  #pragma unroll
  for (int i = 0; i < 8; ++i)
    #pragma unroll
    for (int j = 0; j < 4; ++j)
      acc[i][j] = f32x4{0.f, 0.f, 0.f, 0.f};

  short8 a[4][2], b[4][2];

  // One tile = 4 phases; each phase: {frag ds_reads | stage ONE half} ->
  // barrier -> setprio(1) 16 MFMA setprio(0) -> barrier. Iter-end: counted
  // vmcnt(6) (3 halves = 6 loads may fly) unless DRAIN (kernel tail).
#define DO_TILE(BI, B0P, B0SK, A0P, A0SK, B1P, B1SK, A1P, A1SK, DRAIN)         \
  do {                                                                         \
    /* ---- ph0: read A0(t)+B0(t); stage B0(t+1) -> other buf ---- */          \
    _Pragma("unroll") for (int mf = 0; mf < 4; ++mf) {                         \
      a[mf][0] = LDAF(BI, mf, 0); a[mf][1] = LDAF(BI, mf, 1); }                \
    _Pragma("unroll") for (int nf = 0; nf < 2; ++nf) {                         \
      b[nf][0] = LDBF(BI, nf, 0); b[nf][1] = LDBF(BI, nf, 1); }                \
    if (!(B0SK)) STG_B((BI) ^ 1, 0, B0P);                                      \
    __builtin_amdgcn_s_barrier();                                              \
    __builtin_amdgcn_s_setprio(1);                                             \
    _Pragma("unroll") for (int mf = 0; mf < 4; ++mf) {                         \
      MM(mf, 0, 0); MM(mf, 0, 1); MM(mf, 1, 0); MM(mf, 1, 1); }                \
    __builtin_amdgcn_s_setprio(0);                                             \
    __builtin_amdgcn_s_barrier();                                              \
    /* ---- ph1: read B1(t); stage A0(t+2) (A0(t) consumed in ph0) ---- */     \
    _Pragma("unroll") for (int nf = 2; nf < 4; ++nf) {                         \
      b[nf][0] = LDBF(BI, nf, 0); b[nf][1] = LDBF(BI, nf, 1); }                \
    if (!(A0SK)) STG_A(BI, 0, A0P);                                            \
    __builtin_amdgcn_s_barrier();                                              \
    __builtin_amdgcn_s_setprio(1);                                             \
    _Pragma("unroll") for (int mf = 0; mf < 4; ++mf) {                         \
      MM(mf, 2, 0); MM(mf, 2, 1); MM(mf, 3, 0); MM(mf, 3, 1); }                \
    __builtin_amdgcn_s_setprio(0);                                             \
    __builtin_amdgcn_s_barrier();                                              \
    /* ---- ph2: read A1(t); stage B1(t+2) (B1(t) consumed in ph1) ---- */     \
    _Pragma("unroll") for (int i = 0; i < 4; ++i) {                            \
      a[i][0] = LDAF(BI, 4 + i, 0); a[i][1] = LDAF(BI, 4 + i, 1); }            \
    if (!(B1SK)) STG_B(BI, 1, B1P);                                            \
    __builtin_amdgcn_s_barrier();                                              \
    __builtin_amdgcn_s_setprio(1);                                             \
    _Pragma("unroll") for (int i = 0; i < 4; ++i) {                            \
      MM(4 + i, 2, 0); MM(4 + i, 2, 1); MM(4 + i, 3, 0); MM(4 + i, 3, 1); }    \
    __builtin_amdgcn_s_setprio(0);                                             \
    __builtin_amdgcn_s_barrier();                                              \
    /* ---- ph3: stage A1(t+2) (A1(t) consumed in ph2) ---- */                 \
    if (!(A1SK)) STG_A(BI, 1, A1P);                                            \
    __builtin_amdgcn_s_barrier();                                              \
    __builtin_amdgcn_s_setprio(1);                                             \
    _Pragma("unroll") for (int i = 0; i < 4; ++i) {                            \
      MM(4 + i, 0, 0); MM(4 + i, 0, 1); MM(4 + i, 1, 0); MM(4 + i, 1, 1); }    \
    __builtin_amdgcn_s_setprio(0);                                             \
    if (DRAIN) { asm volatile("s_waitcnt vmcnt(0)" ::: "memory"); }            \
    else       { asm volatile("s_waitcnt vmcnt(6)" ::: "memory"); }            \
    __builtin_amdgcn_s_barrier();                                              \
  } while (0)

  // ---- prologue (once): tile0 all 4 halves + tile1 {A0,B1,A1}. Issue order
  // matches steady state; tile0's ph0 then stages B0(1), completing tile1.
  {
    const u16* Au0 = X + (size_t)(u2 * 256) * D_IN;   // g=0 base
    STG_A(0, 0, Au0);            // A0(0)
    STG_B(0, 1, Bu);             // B1(0)
    STG_A(0, 1, Au0);            // A1(0)
    STG_B(0, 0, Bu);             // B0(0)
    STG_A(1, 0, Au0 + BK);       // A0(1)
    STG_B(1, 1, Bu + BK);        // B1(1)
    STG_A(1, 1, Au0 + BK);       // A1(1)
    asm volatile("s_waitcnt lgkmcnt(0)" ::: "memory");  // param ds_writes done
    asm volatile("s_waitcnt vmcnt(6)" ::: "memory");    // tile0 (8 oldest) landed
    __builtin_amdgcn_s_barrier();
  }

  #pragma unroll 1
  for (int g = 0; g < NSEG; ++g) {
    const u16* AuC = X + (size_t)((g * 8 + u2) * 256) * D_IN;
    const u16* AuN = AuC + (size_t)(8 * 256) * D_IN;   // next segment (g<7)
    const bool lastseg = (g == NSEG - 1);

    #pragma unroll 1
    for (int j = 0; j < KTILES / 2; ++j) {
      const int kt0 = 2 * j;
      const int kp1 = kt0 + 1;          // 1..21 (always in-segment)
      const int kp2 = kt0 + 2;          // 2..22 (22 wraps to next seg tile 0)
      const int kp3 = kt0 + 3;          // 3..23
      const bool w2f = (kp2 >= KTILES), w3f = (kp3 >= KTILES);
      const int k2m = w2f ? kp2 - KTILES : kp2;
      const int k3m = w3f ? kp3 - KTILES : kp3;
      const u16* Bp1 = Bu + kp1 * BK;
      const u16* Bp2 = Bu + k2m * BK;
      const u16* Bp3 = Bu + k3m * BK;
      const u16* Ap2 = (w2f ? AuN : AuC) + k2m * BK;
      const u16* Ap3 = (w3f ? AuN : AuC) + k3m * BK;
      const bool sk2 = lastseg && w2f;  // no segment after the last
      const bool sk3 = lastseg && w3f;
      const bool drain = lastseg && (j == KTILES / 2 - 1);

      DO_TILE(0, Bp1, false, Ap2, sk2, Bp2, sk2, Ap2, sk2, drain);
      DO_TILE(1, Bp2, sk2,   Ap3, sk3, Bp3, sk3, Ap3, sk3, drain);
    }

    // ---- fused epilogue (per segment): relu(acc+b1).W2, 4-wave combine ----
    // acc[mf][nf] elem (quad,r): row=mf*32+wm*16+quad*4+r, col=nf*64+wn*16+l15
    {
      float b1v[4], w2v[4][3];
      #pragma unroll
      for (int nf = 0; nf < 4; ++nf) {
        int col = nf * 64 + wn16l;
        b1v[nf] = b1L[col];
        #pragma unroll
        for (int p = 0; p < 3; ++p) w2v[nf][p] = w2L[col * 3 + p];
      }
      const int m0 = (g * 8 + u2) * 256;

      #pragma unroll
      for (int mf = 0; mf < 8; ++mf) {
        float ps[4][3];
        #pragma unroll
        for (int r = 0; r < 4; ++r)
          #pragma unroll
          for (int p = 0; p < 3; ++p) ps[r][p] = 0.f;

        #pragma unroll
        for (int nf = 0; nf < 4; ++nf)
          #pragma unroll
          for (int r = 0; r < 4; ++r) {
            float h = acc[mf][nf][r] + b1v[nf];
            h = h > 0.f ? h : 0.f;
            #pragma unroll
            for (int p = 0; p < 3; ++p)
              ps[r][p] = fmaf(h, w2v[nf][p], ps[r][p]);
          }

        // sum over the 16 column-lanes (xor on low 4 lane bits stays in-quad)
        #pragma unroll
        for (int mask = 1; mask < 16; mask <<= 1)
          #pragma unroll
          for (int r = 0; r < 4; ++r)
            #pragma unroll
            for (int p = 0; p < 3; ++p)
              ps[r][p] += __shfl_xor(ps[r][p], mask, 64);

        if (l15 == 0) {
          int row = mf * 32 + wm * 16 + quad * 4;          // +r below
          #pragma unroll
          for (int r = 0; r < 4; ++r)
            #pragma unroll
            for (int p = 0; p < 3; ++p)
              scr[((row + r) * 3 + p) * 4 + wn] = ps[r][p];
        }
      }
      // raw barrier (NOT __syncthreads: must not drain in-flight DMA vmcnt)
      asm volatile("s_waitcnt lgkmcnt(0)" ::: "memory");
      __builtin_amdgcn_s_barrier();

      for (int i = tid; i < BM * 3; i += 512) {
        int row = i / 3, p = i - row * 3;
        float v = scr[i * 4 + 0] + scr[i * 4 + 1] + scr[i * 4 + 2]
                + scr[i * 4 + 3] + b2L[p];
        out[(size_t)(m0 + row) * (N_HEADS * 3) + head * 3 + p] = v;
      }

      #pragma unroll
      for (int i = 0; i < 8; ++i)
        #pragma unroll
        for (int jj = 0; jj < 4; ++jj)
          acc[i][jj] = f32x4{0.f, 0.f, 0.f, 0.f};
      // no trailing barrier needed: next tile reads As/Bs (disjoint from
      // scr); its own ph0-end barrier orders everything. scr not rewritten
      // until next epilogue, 22 tiles of barriers away.
    }
  }

#undef STG_A
#undef STG_B
#undef LDAF
#undef LDBF
#undef MM
#undef DO_TILE
}

extern "C" void kernel_launch(void* const* d_in, const int* in_sizes, int n_in,
                              void* d_out, int out_size, void* d_ws, size_t ws_size,
                              hipStream_t stream) {
  const float* X  = (const float*)d_in[0];
  const float* W1 = (const float*)d_in[1];
  const float* b1 = (const float*)d_in[2];
  const float* W2 = (const float*)d_in[3];
  const float* b2 = (const float*)d_in[4];

  // ws: Xb 46,137,344 | W1T 23,068,672  = 69,206,016 B (proven fits)
  u16* Xb  = (u16*)d_ws;
  u16* W1T = (u16*)((char*)d_ws + (size_t)BATCH * D_IN * 2);

  convert_x<<<(BATCH * D_IN / 4) / 256, 256, 0, stream>>>(
      (const float4*)X, (ushort4*)Xb);

  transpose_w1<<<dim3(D_IN / 64, D_HID / 64, N_HEADS), dim3(64, 4), 0, stream>>>(W1, W1T);

  mano_gemm<<<dim3(256), 512, 0, stream>>>(
      Xb, W1T, b1, W2, b2, (float*)d_out);
}

// Round 3
// 544.381 us; speedup vs baseline: 1.1111x; 1.0152x over previous
//
#include <hip/hip_runtime.h>
#include <hip/hip_bf16.h>
#include <stdint.h>

#define D_IN    1408
#define D_HID   256
#define N_HEADS 32
#define BATCH   16384

#define BM 256            // rows per block
#define BN 256            // full head of hidden units
#define BK 64
#define KTILES (D_IN / BK)   // 22, exact (even -> static double-buffer parity)
#define NSEG 8               // segments per persistent block

typedef unsigned short u16;
typedef short short8 __attribute__((ext_vector_type(8)));
typedef float f32x4 __attribute__((ext_vector_type(4)));

// All inputs and the output are float32 (reference dtypes); compute is bf16
// MFMA (absmax 7.8e-3 vs threshold 2.4e-2, verified R1/R2).
__device__ __forceinline__ u16 f2b(float f) {
  __hip_bfloat16 h = __float2bfloat16(f);
  return *(u16*)&h;
}

// async global->LDS DMA, 16B/lane; LDS dest = wave-uniform base + lane*16.
__device__ __forceinline__ void gload_lds16(const void* g, void* l) {
  __builtin_amdgcn_global_load_lds(
      (const __attribute__((address_space(1))) uint32_t*)((const uint32_t*)g),
      (__attribute__((address_space(3))) uint32_t*)((uint32_t*)l),
      16, 0, 0);
}

// ---------------------------------------------------------------------------
// Kernel 0: X f32 [16384][1408] -> Xb bf16
// ---------------------------------------------------------------------------
__global__ void convert_x(const float4* __restrict__ X, ushort4* __restrict__ Xb) {
  int i = blockIdx.x * blockDim.x + threadIdx.x;   // 5,767,168 float4s exactly
  float4 v = X[i];
  ushort4 o;
  o.x = f2b(v.x); o.y = f2b(v.y); o.z = f2b(v.z); o.w = f2b(v.w);
  Xb[i] = o;
}

// ---------------------------------------------------------------------------
// Kernel 1: W1 f32 [32][1408][256] -> W1T bf16 [32][256][1408]
// ---------------------------------------------------------------------------
__global__ void transpose_w1(const float* __restrict__ W1, u16* __restrict__ W1T) {
  __shared__ u16 tile[64][68];      // pad to 68 (136B rows) for read spread
  const int h = blockIdx.z;
  const int f0 = blockIdx.x * 64;
  const int o0 = blockIdx.y * 64;
  const int tx = threadIdx.x;       // 0..63
  const int ty = threadIdx.y;       // 0..3
  const size_t ib = (size_t)h * D_IN * D_HID;
  #pragma unroll
  for (int i = ty; i < 64; i += 4)
    tile[i][tx] = f2b(W1[ib + (size_t)(f0 + i) * D_HID + o0 + tx]);
  __syncthreads();
  const size_t ob = (size_t)h * D_HID * D_IN;
  // 256 threads; 16 threads per output row (4 cols each) -> 16 rows/pass.
  #pragma unroll
  for (int pass = 0; pass < 4; ++pass) {
    int r = pass * 16 + ty * 4 + (tx >> 4);  // 0..63
    int c = (tx & 15) * 4;                   // 0..60
    ushort4 v;
    v.x = tile[c + 0][r]; v.y = tile[c + 1][r];
    v.z = tile[c + 2][r]; v.w = tile[c + 3][r];
    *(ushort4*)&W1T[ob + (size_t)(o0 + r) * D_IN + f0 + c] = v;
  }
}

// ---------------------------------------------------------------------------
// Kernel 2: PERSISTENT 256x256 8-wave fused GEMM, SINGLE-BARRIER phases.
//
// R2 post-mortem: 5700 cy/tile = MFMA 2480 + LDS-read 2300 + barriers ~800
// SERIALIZED -- the per-phase {reads -> barrier1 -> MFMA -> barrier2}
// lockstep keeps the LDS pipe idle during MFMA and vice versa. Hazard audit:
// barrier1 protects nothing. Every stage in phase p overwrites a region
// whose last reads were issued in phase p-1 and completed before each
// wave's own lgkm wait, i.e. before barrier2(p-1) -- which remains. Reads
// target regions staged >=1 tile ago, protected by the tile-end
// vmcnt(6)+barrier (unchanged). So this rev REMOVES barrier1: phase =
// {reads | stage-issue -> (slip) -> MFMA -> barrier}. A wave that finishes
// its reads enters MFMA while its SIMD-mate still reads -> LDS pipe overlaps
// matrix pipe; setprio(1) now has role-diverse waves to arbitrate (T5).
// Slip is bounded by barrier2, so the staging-safety proof is unchanged.
// Everything else identical to R2 (verified passing, absmax 7.8e-3).
// ---------------------------------------------------------------------------
__global__ __launch_bounds__(512, 2) void mano_gemm(
    const u16* __restrict__ X,               // [16384][1408] bf16 (ws)
    const u16* __restrict__ W1T,             // [32][256][1408] bf16 (ws)
    const float* __restrict__ b1,            // [32][256] f32
    const float* __restrict__ W2,            // [32][256][3] f32
    const float* __restrict__ b2,            // [32][3] f32
    float* __restrict__ out)                 // [16384][96] f32 (d_out)
{
  __shared__ __align__(16) u16 As[2][BM * BK];   // 2 x 32 KB
  __shared__ __align__(16) u16 Bs[2][BN * BK];   // 2 x 32 KB
  __shared__ __align__(16) float scr[3072];      // 12 KB epilogue scratch
  __shared__ float b1L[256];                     // head-constant params
  __shared__ float w2L[768];
  __shared__ float b2L[3];

  const int tid  = threadIdx.x;
  const int lane = tid & 63;
  const int wid  = tid >> 6;        // 0..7
  const int quad = lane >> 4;
  const int l15  = lane & 15;
  const int wm   = wid >> 2;        // 0..1
  const int wn   = wid & 3;         // 0..3

  const int bid  = blockIdx.x;              // 0..255
  const int head = (bid & 7) * 4 + ((bid >> 3) & 3);   // constant per block
  const int u2   = bid >> 5;                           // 0..7

  const u16* Bu = W1T + (size_t)head * D_HID * D_IN;

  // ---- head-constant params -> LDS (once; epilogues then do zero VMEM) ----
  if (tid < 256) b1L[tid] = b1[head * D_HID + tid];
  for (int i = tid; i < 768; i += 512) w2L[i] = W2[(size_t)head * D_HID * 3 + i];
  if (tid < 3)  b2L[tid] = b2[head * 3 + tid];

  // staging: LDS chunk ci(16B) of a 128-row half holds global
  // [row=ci>>3][k8=(ci&7)^(row&7)] (XOR pre-swizzled source, linear LDS).
  int off[2][2];   // [half][c] global u16 offset (row*D_IN + k8*8)
  #pragma unroll
  for (int c = 0; c < 2; ++c) {
    int ci = c * 512 + tid;
    int rl = ci >> 3;                 // 0..127
    int k8 = (ci & 7) ^ (rl & 7);
    #pragma unroll
    for (int h = 0; h < 2; ++h)
      off[h][c] = (h * 128 + rl) * D_IN + k8 * 8;
  }

#define STG_A(BI, H, P) do { _Pragma("unroll")                                 \
    for (int c = 0; c < 2; ++c)                                                \
      gload_lds16((P) + off[H][c],                                             \
                  &As[BI][((H) * 1024 + c * 512 + wid * 64) * 8]); } while (0)
#define STG_B(BI, H, P) do { _Pragma("unroll")                                 \
    for (int c = 0; c < 2; ++c)                                                \
      gload_lds16((P) + off[H][c],                                             \
                  &Bs[BI][((H) * 1024 + c * 512 + wid * 64) * 8]); } while (0)

  // frag read addressing: A row = mf*32+wm*16+l15, B row = nf*64+wn*16+l15;
  // phys chunk = (ks*4+quad) ^ (row&7), row&7 == l15&7.
  const int wm16l = wm * 16 + l15;
  const int wn16l = wn * 16 + l15;
  const int rx  = l15 & 7;
  const int co0 = (quad ^ rx) * 16;
  const int co1 = ((4 + quad) ^ rx) * 16;

#define LDAF(BI, mf, ks)                                                       \
  (*(const short8*)((const char*)&As[BI][0] +                                  \
                    ((mf) * 32 + wm16l) * 128 + ((ks) ? co1 : co0)))
#define LDBF(BI, nf, ks)                                                       \
  (*(const short8*)((const char*)&Bs[BI][0] +                                  \
                    (nf) * 8192 + wn16l * 128 + ((ks) ? co1 : co0)))
#define MM(mi, nj, ks)                                                         \
  acc[mi][nj] = __builtin_amdgcn_mfma_f32_16x16x32_bf16(                       \
      a[(mi) & 3][ks], b[nj][ks], acc[mi][nj], 0, 0, 0)

  f32x4 acc[8][4];
  #pragma unroll
  for (int i = 0; i < 8; ++i)
    #pragma unroll
    for (int j = 0; j < 4; ++j)
      acc[i][j] = f32x4{0.f, 0.f, 0.f, 0.f};

  short8 a[4][2], b[4][2];

  // One tile = 4 phases; each phase: {frag ds_reads | stage ONE half} ->
  // (no barrier: waves slip into MFMA while SIMD-mates read) -> setprio(1)
  // 16 MFMA setprio(0) -> barrier. Iter-end: counted vmcnt(6) (3 halves =
  // 6 loads may fly) unless DRAIN (kernel tail).
#define DO_TILE(BI, B0P, B0SK, A0P, A0SK, B1P, B1SK, A1P, A1SK, DRAIN)         \
  do {                                                                         \
    /* ---- ph0: read A0(t)+B0(t); stage B0(t+1) -> other buf ---- */          \
    _Pragma("unroll") for (int mf = 0; mf < 4; ++mf) {                         \
      a[mf][0] = LDAF(BI, mf, 0); a[mf][1] = LDAF(BI, mf, 1); }                \
    _Pragma("unroll") for (int nf = 0; nf < 2; ++nf) {                         \
      b[nf][0] = LDBF(BI, nf, 0); b[nf][1] = LDBF(BI, nf, 1); }                \
    if (!(B0SK)) STG_B((BI) ^ 1, 0, B0P);                                      \
    __builtin_amdgcn_s_setprio(1);                                             \
    _Pragma("unroll") for (int mf = 0; mf < 4; ++mf) {                         \
      MM(mf, 0, 0); MM(mf, 0, 1); MM(mf, 1, 0); MM(mf, 1, 1); }                \
    __builtin_amdgcn_s_setprio(0);                                             \
    __builtin_amdgcn_s_barrier();                                              \
    /* ---- ph1: read B1(t); stage A0(t+2) (A0(t) consumed in ph0) ---- */     \
    _Pragma("unroll") for (int nf = 2; nf < 4; ++nf) {                         \
      b[nf][0] = LDBF(BI, nf, 0); b[nf][1] = LDBF(BI, nf, 1); }                \
    if (!(A0SK)) STG_A(BI, 0, A0P);                                            \
    __builtin_amdgcn_s_setprio(1);                                             \
    _Pragma("unroll") for (int mf = 0; mf < 4; ++mf) {                         \
      MM(mf, 2, 0); MM(mf, 2, 1); MM(mf, 3, 0); MM(mf, 3, 1); }                \
    __builtin_amdgcn_s_setprio(0);                                             \
    __builtin_amdgcn_s_barrier();                                              \
    /* ---- ph2: read A1(t); stage B1(t+2) (B1(t) consumed in ph1) ---- */     \
    _Pragma("unroll") for (int i = 0; i < 4; ++i) {                            \
      a[i][0] = LDAF(BI, 4 + i, 0); a[i][1] = LDAF(BI, 4 + i, 1); }            \
    if (!(B1SK)) STG_B(BI, 1, B1P);                                            \
    __builtin_amdgcn_s_setprio(1);                                             \
    _Pragma("unroll") for (int i = 0; i < 4; ++i) {                            \
      MM(4 + i, 2, 0); MM(4 + i, 2, 1); MM(4 + i, 3, 0); MM(4 + i, 3, 1); }    \
    __builtin_amdgcn_s_setprio(0);                                             \
    __builtin_amdgcn_s_barrier();                                              \
    /* ---- ph3: stage A1(t+2) (A1(t) consumed in ph2) ---- */                 \
    if (!(A1SK)) STG_A(BI, 1, A1P);                                            \
    __builtin_amdgcn_s_setprio(1);                                             \
    _Pragma("unroll") for (int i = 0; i < 4; ++i) {                            \
      MM(4 + i, 0, 0); MM(4 + i, 0, 1); MM(4 + i, 1, 0); MM(4 + i, 1, 1); }    \
    __builtin_amdgcn_s_setprio(0);                                             \
    if (DRAIN) { asm volatile("s_waitcnt vmcnt(0)" ::: "memory"); }            \
    else       { asm volatile("s_waitcnt vmcnt(6)" ::: "memory"); }            \
    __builtin_amdgcn_s_barrier();                                              \
  } while (0)

  // ---- prologue (once): tile0 all 4 halves + tile1 {A0,B1,A1}. Issue order
  // matches steady state; tile0's ph0 then stages B0(1), completing tile1.
  {
    const u16* Au0 = X + (size_t)(u2 * 256) * D_IN;   // g=0 base
    STG_A(0, 0, Au0);            // A0(0)
    STG_B(0, 1, Bu);             // B1(0)
    STG_A(0, 1, Au0);            // A1(0)
    STG_B(0, 0, Bu);             // B0(0)
    STG_A(1, 0, Au0 + BK);       // A0(1)
    STG_B(1, 1, Bu + BK);        // B1(1)
    STG_A(1, 1, Au0 + BK);       // A1(1)
    asm volatile("s_waitcnt lgkmcnt(0)" ::: "memory");  // param ds_writes done
    asm volatile("s_waitcnt vmcnt(6)" ::: "memory");    // tile0 (8 oldest) landed
    __builtin_amdgcn_s_barrier();
  }

  #pragma unroll 1
  for (int g = 0; g < NSEG; ++g) {
    const u16* AuC = X + (size_t)((g * 8 + u2) * 256) * D_IN;
    const u16* AuN = AuC + (size_t)(8 * 256) * D_IN;   // next segment (g<7)
    const bool lastseg = (g == NSEG - 1);

    #pragma unroll 1
    for (int j = 0; j < KTILES / 2; ++j) {
      const int kt0 = 2 * j;
      const int kp1 = kt0 + 1;          // 1..21 (always in-segment)
      const int kp2 = kt0 + 2;          // 2..22 (22 wraps to next seg tile 0)
      const int kp3 = kt0 + 3;          // 3..23
      const bool w2f = (kp2 >= KTILES), w3f = (kp3 >= KTILES);
      const int k2m = w2f ? kp2 - KTILES : kp2;
      const int k3m = w3f ? kp3 - KTILES : kp3;
      const u16* Bp1 = Bu + kp1 * BK;
      const u16* Bp2 = Bu + k2m * BK;
      const u16* Bp3 = Bu + k3m * BK;
      const u16* Ap2 = (w2f ? AuN : AuC) + k2m * BK;
      const u16* Ap3 = (w3f ? AuN : AuC) + k3m * BK;
      const bool sk2 = lastseg && w2f;  // no segment after the last
      const bool sk3 = lastseg && w3f;
      const bool drain = lastseg && (j == KTILES / 2 - 1);

      DO_TILE(0, Bp1, false, Ap2, sk2, Bp2, sk2, Ap2, sk2, drain);
      DO_TILE(1, Bp2, sk2,   Ap3, sk3, Bp3, sk3, Ap3, sk3, drain);
    }

    // ---- fused epilogue (per segment): relu(acc+b1).W2, 4-wave combine ----
    // acc[mf][nf] elem (quad,r): row=mf*32+wm*16+quad*4+r, col=nf*64+wn*16+l15
    {
      float b1v[4], w2v[4][3];
      #pragma unroll
      for (int nf = 0; nf < 4; ++nf) {
        int col = nf * 64 + wn16l;
        b1v[nf] = b1L[col];
        #pragma unroll
        for (int p = 0; p < 3; ++p) w2v[nf][p] = w2L[col * 3 + p];
      }
      const int m0 = (g * 8 + u2) * 256;

      #pragma unroll
      for (int mf = 0; mf < 8; ++mf) {
        float ps[4][3];
        #pragma unroll
        for (int r = 0; r < 4; ++r)
          #pragma unroll
          for (int p = 0; p < 3; ++p) ps[r][p] = 0.f;

        #pragma unroll
        for (int nf = 0; nf < 4; ++nf)
          #pragma unroll
          for (int r = 0; r < 4; ++r) {
            float h = acc[mf][nf][r] + b1v[nf];
            h = h > 0.f ? h : 0.f;
            #pragma unroll
            for (int p = 0; p < 3; ++p)
              ps[r][p] = fmaf(h, w2v[nf][p], ps[r][p]);
          }

        // sum over the 16 column-lanes (xor on low 4 lane bits stays in-quad)
        #pragma unroll
        for (int mask = 1; mask < 16; mask <<= 1)
          #pragma unroll
          for (int r = 0; r < 4; ++r)
            #pragma unroll
            for (int p = 0; p < 3; ++p)
              ps[r][p] += __shfl_xor(ps[r][p], mask, 64);

        if (l15 == 0) {
          int row = mf * 32 + wm * 16 + quad * 4;          // +r below
          #pragma unroll
          for (int r = 0; r < 4; ++r)
            #pragma unroll
            for (int p = 0; p < 3; ++p)
              scr[((row + r) * 3 + p) * 4 + wn] = ps[r][p];
        }
      }
      // raw barrier (NOT __syncthreads: must not drain in-flight DMA vmcnt)
      asm volatile("s_waitcnt lgkmcnt(0)" ::: "memory");
      __builtin_amdgcn_s_barrier();

      for (int i = tid; i < BM * 3; i += 512) {
        int row = i / 3, p = i - row * 3;
        float v = scr[i * 4 + 0] + scr[i * 4 + 1] + scr[i * 4 + 2]
                + scr[i * 4 + 3] + b2L[p];
        out[(size_t)(m0 + row) * (N_HEADS * 3) + head * 3 + p] = v;
      }

      #pragma unroll
      for (int i = 0; i < 8; ++i)
        #pragma unroll
        for (int jj = 0; jj < 4; ++jj)
          acc[i][jj] = f32x4{0.f, 0.f, 0.f, 0.f};
      // no trailing barrier needed: next tile reads As/Bs (disjoint from
      // scr); its own phase-end barrier orders everything. scr not rewritten
      // until next epilogue, 22 tiles of barriers away.
    }
  }

#undef STG_A
#undef STG_B
#undef LDAF
#undef LDBF
#undef MM
#undef DO_TILE
}

extern "C" void kernel_launch(void* const* d_in, const int* in_sizes, int n_in,
                              void* d_out, int out_size, void* d_ws, size_t ws_size,
                              hipStream_t stream) {
  const float* X  = (const float*)d_in[0];
  const float* W1 = (const float*)d_in[1];
  const float* b1 = (const float*)d_in[2];
  const float* W2 = (const float*)d_in[3];
  const float* b2 = (const float*)d_in[4];

  // ws: Xb 46,137,344 | W1T 23,068,672  = 69,206,016 B (proven fits)
  u16* Xb  = (u16*)d_ws;
  u16* W1T = (u16*)((char*)d_ws + (size_t)BATCH * D_IN * 2);

  convert_x<<<(BATCH * D_IN / 4) / 256, 256, 0, stream>>>(
      (const float4*)X, (ushort4*)Xb);

  transpose_w1<<<dim3(D_IN / 64, D_HID / 64, N_HEADS), dim3(64, 4), 0, stream>>>(W1, W1T);

  mano_gemm<<<dim3(256), 512, 0, stream>>>(
      Xb, W1T, b1, W2, b2, (float*)d_out);
}